// Round 1
// baseline (407.913 us; speedup 1.0000x reference)
//
#include <hip/hip_runtime.h>

// Contracter: out[z,u,k] = sum_{i,j} x1[z,u,i] * x2[z,u,j] * ww3j[u,k,i,j]
// where ww3j[u,k,i,j] = sum_p weights[u,p] * w3j[p,k,i,j].
// Z=50000, MUL=64 channels, BASE=9 (irreps 1+3+5), 11 paths. All fp32.
//
// v2 strategy (fixing the uncoalesced-VMEM latency bound of v1):
//  - fold_kernel: fold per-channel path weights into dense ww (64 x 729).
//  - tp_kernel: block = 64 z-rows x 8 channels. Stage x1/x2 tiles
//    [64 z][72 floats] in LDS via fully-coalesced float4 loads (contiguous
//    288B row segments instead of per-lane 2304B-strided 36B slices that
//    cost 64 cache lines per vmem instruction).
//  - compute keeps lane=z, wave-uniform u -> ww row stays on the scalar
//    pipe (SMRD) feeding the dense 729-FMA contraction.
//  - XOR bank swizzle (c ^ ((row>>2)&7)) makes the stride-72 per-lane
//    ds_read_b32 conflict-free (raw stride 72 floats = 16-way conflict).
//  - each wave owns LDS columns [18w, 18w+18) (bijective swizzle keeps
//    ownership disjoint), so outputs are written back into s1 without an
//    extra barrier; final coalesced float4 store from LDS.
//  - XCD swizzle: all 8 u-chunks of one z-tile on one XCD (zt = xcd + 8q)
//    so boundary lines and L3-resident rows stay XCD-local.

#define MUL   64
#define BASE  9
#define NPATH 11
#define ZT    64            // z rows per tile
#define UC    8             // u channels per block
#define TW    (UC * BASE)   // 72 floats per staged row
#define NF4   (ZT * TW / 4) // 1152 float4 per tile

__global__ __launch_bounds__(256) void fold_kernel(
    const float* __restrict__ weights,   // (64, 11)
    const float* __restrict__ w3j,       // (11, 729)
    float*       __restrict__ ww)        // (64, 729) out
{
    int u = blockIdx.x / 3;                          // 0..63
    int t = (blockIdx.x % 3) * 256 + threadIdx.x;    // 0..767
    if (t >= 729) return;
    float acc = 0.f;
#pragma unroll
    for (int p = 0; p < NPATH; ++p)
        acc = fmaf(weights[u * NPATH + p], w3j[p * 729 + t], acc);
    ww[u * 729 + t] = acc;
}

__global__ __launch_bounds__(256, 4) void tp_kernel(
    const float* __restrict__ x1,
    const float* __restrict__ x2,
    const float* __restrict__ ww,        // (64, 729)
    float*       __restrict__ out,
    int Z, int n_zt)
{
    __shared__ float s1[ZT * TW];   // x1 tile, later reused for out tile
    __shared__ float s2[ZT * TW];   // x2 tile

    int b   = blockIdx.x;
    int xcd = b & 7;
    int t   = b >> 3;
    int uc  = t & 7;        // u-chunk 0..7
    int q   = t >> 3;
    int zt  = xcd + 8 * q;  // all 8 u-chunks of a z-tile on one XCD
    if (zt >= n_zt) return;

    int tid  = threadIdx.x;
    int wave = tid >> 6;
    int lane = tid & 63;

    const size_t gbase = (size_t)zt * ZT * 576 + (size_t)uc * TW;

    // ---- Stage x1/x2 tiles: 64 rows x 72 floats, XOR bank swizzle ----
#pragma unroll
    for (int rep = 0; rep < 5; ++rep) {
        int f = rep * 256 + tid;          // float4 index in [0, 1152)
        if (f < NF4) {
            int r  = f / 18;              // z-row within tile
            int c4 = f % 18;              // float4 column
            int z  = zt * ZT + r;
            float4 v1 = make_float4(0.f, 0.f, 0.f, 0.f);
            float4 v2 = make_float4(0.f, 0.f, 0.f, 0.f);
            if (z < Z) {
                const size_t g = gbase + (size_t)r * 576 + c4 * 4;
                v1 = *(const float4*)(x1 + g);
                v2 = *(const float4*)(x2 + g);
            }
            int a    = (r >> 2) & 7;      // row swizzle key
            int base = r * TW;
            int c    = c4 * 4;
            s1[base + ((c + 0) ^ a)] = v1.x;
            s1[base + ((c + 1) ^ a)] = v1.y;
            s1[base + ((c + 2) ^ a)] = v1.z;
            s1[base + ((c + 3) ^ a)] = v1.w;
            s2[base + ((c + 0) ^ a)] = v2.x;
            s2[base + ((c + 1) ^ a)] = v2.y;
            s2[base + ((c + 2) ^ a)] = v2.z;
            s2[base + ((c + 3) ^ a)] = v2.w;
        }
    }
    __syncthreads();

    // ---- Compute: wave w handles u = uc*8 + 2w + it, lane = z-row ----
    int az   = (lane >> 2) & 7;
    int zrow = lane * TW;
#pragma unroll
    for (int it = 0; it < 2; ++it) {
        int du = wave * 2 + it;                                  // 0..7
        int u  = __builtin_amdgcn_readfirstlane(uc * UC + du);   // uniform
        const float* __restrict__ wrow = ww + u * 729;           // SMRD

        float X1[BASE], X2[BASE];
#pragma unroll
        for (int i = 0; i < BASE; ++i) {
            int c = du * BASE + i;
            X1[i] = s1[zrow + (c ^ az)];
            X2[i] = s2[zrow + (c ^ az)];
        }

        // 81-element outer product, per lane.
        float r_[BASE * BASE];
#pragma unroll
        for (int i = 0; i < BASE; ++i)
#pragma unroll
            for (int j = 0; j < BASE; ++j)
                r_[i * BASE + j] = X1[i] * X2[j];

        // Dense contraction: o[k] = sum_t wrow[k*81+t] * r_[t].
        // t-outer / k-inner gives 9 independent FMA chains (ILP).
        float o[BASE];
#pragma unroll
        for (int k = 0; k < BASE; ++k) o[k] = 0.f;
#pragma unroll
        for (int tt = 0; tt < BASE * BASE; ++tt)
#pragma unroll
            for (int k = 0; k < BASE; ++k)
                o[k] = fmaf(wrow[k * 81 + tt], r_[tt], o[k]);

        // Write output into this wave's own (swizzled) columns of s1.
        // Swizzle is a bijection per row, so wave column-ownership stays
        // disjoint; only same-wave RAW on its own columns (program order).
#pragma unroll
        for (int k = 0; k < BASE; ++k)
            s1[zrow + ((du * BASE + k) ^ az)] = o[k];
    }
    __syncthreads();

    // ---- Coalesced float4 store of the out tile from s1 ----
#pragma unroll
    for (int rep = 0; rep < 5; ++rep) {
        int f = rep * 256 + tid;
        if (f < NF4) {
            int r  = f / 18;
            int c4 = f % 18;
            int z  = zt * ZT + r;
            if (z < Z) {
                int a    = (r >> 2) & 7;
                int base = r * TW;
                int c    = c4 * 4;
                float4 v;
                v.x = s1[base + ((c + 0) ^ a)];
                v.y = s1[base + ((c + 1) ^ a)];
                v.z = s1[base + ((c + 2) ^ a)];
                v.w = s1[base + ((c + 3) ^ a)];
                *(float4*)(out + gbase + (size_t)r * 576 + c4 * 4) = v;
            }
        }
    }
}

extern "C" void kernel_launch(void* const* d_in, const int* in_sizes, int n_in,
                              void* d_out, int out_size, void* d_ws, size_t ws_size,
                              hipStream_t stream) {
    const float* x1  = (const float*)d_in[0];
    const float* x2  = (const float*)d_in[1];
    const float* w   = (const float*)d_in[2];   // (64, 11)
    const float* w3j = (const float*)d_in[3];   // (11, 9, 9, 9)
    float* out = (float*)d_out;
    float* ww  = (float*)d_ws;                  // (64, 729) scratch

    int Z = in_sizes[0] / (MUL * BASE);

    // Fold weights into CG tensor: 64 channels x 3 blocks of 256 covering 729.
    fold_kernel<<<MUL * 3, 256, 0, stream>>>(w, w3j, ww);

    int n_zt = (Z + ZT - 1) / ZT;
    int Q    = (n_zt + 7) / 8;
    int grid = 8 * 8 * Q;   // xcd (8) x u-chunk (8) x q
    tp_kernel<<<grid, 256, 0, stream>>>(x1, x2, ww, out, Z, n_zt);
}

// Round 2
// 404.051 us; speedup vs baseline: 1.0096x; 1.0096x over previous
//
#include <hip/hip_runtime.h>

// Contracter: out[z,u,k] = sum_{i,j} x1[z,u,i] * x2[z,u,j] * ww3j[u,k,i,j]
// where ww3j[u,k,i,j] = sum_p weights[u,p] * w3j[p,k,i,j].
// Z=50000, MUL=64 channels, BASE=9 (irreps 1+3+5), 11 paths. All fp32.
//
// v3: v2's structure (coalesced global <-> LDS staging, lane=z compute with
// wave-uniform u feeding the 729-float ww row through the scalar pipe) but
// with a TRANSPOSED padded LDS layout instead of the XOR swizzle that caused
// v2's 6.9M 8-way bank conflicts:
//   s[col][row], row stride 65 floats (65 % 32 == 1).
//   - compute reads  s[c*65 + lane]  -> bank (c+lane)%32 -> 2-way = free,
//     and the per-read address is base(lane) + immediate offset (no VALU).
//   - staging writes s[(4c4+e)*65 + r] -> bank (4c4+e+r)%32 -> <=3-way.
//   - no XOR math; float4 global loads stay intact; LDS side is 8 cheap
//     scalar writes per float4 pair.
// Output is written back into s1's own (disjoint per-wave) columns, then
// stored with coalesced float4 after one barrier.
// XCD swizzle: all 8 u-chunks of one z-tile on one XCD (zt = xcd + 8q).

#define MUL   64
#define BASE  9
#define NPATH 11
#define ZT    64            // z rows per tile
#define UC    8             // u channels per block
#define TW    (UC * BASE)   // 72 staged columns
#define LP    (ZT + 1)      // padded row stride (65: odd -> conflict-free)
#define NF4   (ZT * TW / 4) // 1152 float4 per tile per array

__global__ __launch_bounds__(256) void fold_kernel(
    const float* __restrict__ weights,   // (64, 11)
    const float* __restrict__ w3j,       // (11, 729)
    float*       __restrict__ ww)        // (64, 729) out
{
    int u = blockIdx.x / 3;                          // 0..63
    int t = (blockIdx.x % 3) * 256 + threadIdx.x;    // 0..767
    if (t >= 729) return;
    float acc = 0.f;
#pragma unroll
    for (int p = 0; p < NPATH; ++p)
        acc = fmaf(weights[u * NPATH + p], w3j[p * 729 + t], acc);
    ww[u * 729 + t] = acc;
}

__global__ __launch_bounds__(256, 4) void tp_kernel(
    const float* __restrict__ x1,
    const float* __restrict__ x2,
    const float* __restrict__ ww,        // (64, 729)
    float*       __restrict__ out,
    int Z, int n_zt)
{
    __shared__ float s1[TW * LP];   // x1 tile (transposed), reused for out
    __shared__ float s2[TW * LP];   // x2 tile (transposed)

    int b   = blockIdx.x;
    int xcd = b & 7;
    int t   = b >> 3;
    int uc  = t & 7;        // u-chunk 0..7
    int q   = t >> 3;
    int zt  = xcd + 8 * q;  // all 8 u-chunks of a z-tile on one XCD
    if (zt >= n_zt) return;

    int tid  = threadIdx.x;
    int wave = tid >> 6;
    int lane = tid & 63;

    const size_t gbase = (size_t)zt * ZT * 576 + (size_t)uc * TW;

    // ---- Stage x1/x2: coalesced float4 global loads -> transposed LDS ----
#pragma unroll
    for (int rep = 0; rep < 5; ++rep) {
        int f = rep * 256 + tid;          // float4 index in [0, 1152)
        if (f < NF4) {
            int r  = f / 18;              // z-row within tile
            int c4 = f % 18;              // float4 column
            int z  = zt * ZT + r;
            float4 v1 = make_float4(0.f, 0.f, 0.f, 0.f);
            float4 v2 = make_float4(0.f, 0.f, 0.f, 0.f);
            if (z < Z) {
                const size_t g = gbase + (size_t)r * 576 + c4 * 4;
                v1 = *(const float4*)(x1 + g);
                v2 = *(const float4*)(x2 + g);
            }
            int c = c4 * 4;
            s1[(c + 0) * LP + r] = v1.x;
            s1[(c + 1) * LP + r] = v1.y;
            s1[(c + 2) * LP + r] = v1.z;
            s1[(c + 3) * LP + r] = v1.w;
            s2[(c + 0) * LP + r] = v2.x;
            s2[(c + 1) * LP + r] = v2.y;
            s2[(c + 2) * LP + r] = v2.z;
            s2[(c + 3) * LP + r] = v2.w;
        }
    }
    __syncthreads();

    // ---- Compute: wave w handles du = 2w, 2w+1; lane = z-row ----
#pragma unroll
    for (int it = 0; it < 2; ++it) {
        int du = wave * 2 + it;                                  // 0..7
        int u  = __builtin_amdgcn_readfirstlane(uc * UC + du);   // uniform
        const float* __restrict__ wrow = ww + u * 729;           // SMRD

        // 18 conflict-free ds_read_b32, base = lane, imm-style offsets.
        float X1[BASE], X2[BASE];
#pragma unroll
        for (int i = 0; i < BASE; ++i) {
            int c = du * BASE + i;
            X1[i] = s1[c * LP + lane];
            X2[i] = s2[c * LP + lane];
        }

        // 81-element outer product, per lane.
        float r_[BASE * BASE];
#pragma unroll
        for (int i = 0; i < BASE; ++i)
#pragma unroll
            for (int j = 0; j < BASE; ++j)
                r_[i * BASE + j] = X1[i] * X2[j];

        // Dense contraction: o[k] = sum_t wrow[k*81+t] * r_[t].
        // t-outer / k-inner gives 9 independent FMA chains (ILP).
        float o[BASE];
#pragma unroll
        for (int k = 0; k < BASE; ++k) o[k] = 0.f;
#pragma unroll
        for (int tt = 0; tt < BASE * BASE; ++tt)
#pragma unroll
            for (int k = 0; k < BASE; ++k)
                o[k] = fmaf(wrow[k * 81 + tt], r_[tt], o[k]);

        // Write into this wave's own columns of s1.
        // it=0 writes cols [18w,18w+9), it=1 reads [18w+9,18w+18): disjoint;
        // waves own disjoint column ranges -> no barrier needed here.
#pragma unroll
        for (int k = 0; k < BASE; ++k)
            s1[(du * BASE + k) * LP + lane] = o[k];
    }
    __syncthreads();

    // ---- Coalesced float4 store of the out tile from s1 ----
#pragma unroll
    for (int rep = 0; rep < 5; ++rep) {
        int f = rep * 256 + tid;
        if (f < NF4) {
            int r  = f / 18;
            int c4 = f % 18;
            int z  = zt * ZT + r;
            if (z < Z) {
                int c = c4 * 4;
                float4 v;
                v.x = s1[(c + 0) * LP + r];
                v.y = s1[(c + 1) * LP + r];
                v.z = s1[(c + 2) * LP + r];
                v.w = s1[(c + 3) * LP + r];
                *(float4*)(out + gbase + (size_t)r * 576 + c4 * 4) = v;
            }
        }
    }
}

extern "C" void kernel_launch(void* const* d_in, const int* in_sizes, int n_in,
                              void* d_out, int out_size, void* d_ws, size_t ws_size,
                              hipStream_t stream) {
    const float* x1  = (const float*)d_in[0];
    const float* x2  = (const float*)d_in[1];
    const float* w   = (const float*)d_in[2];   // (64, 11)
    const float* w3j = (const float*)d_in[3];   // (11, 9, 9, 9)
    float* out = (float*)d_out;
    float* ww  = (float*)d_ws;                  // (64, 729) scratch

    int Z = in_sizes[0] / (MUL * BASE);

    // Fold weights into CG tensor: 64 channels x 3 blocks of 256 covering 729.
    fold_kernel<<<MUL * 3, 256, 0, stream>>>(w, w3j, ww);

    int n_zt = (Z + ZT - 1) / ZT;
    int Q    = (n_zt + 7) / 8;
    int grid = 8 * 8 * Q;   // xcd (8) x u-chunk (8) x q
    tp_kernel<<<grid, 256, 0, stream>>>(x1, x2, ww, out, Z, n_zt);
}

// Round 5
// 286.961 us; speedup vs baseline: 1.4215x; 1.4080x over previous
//
#include <hip/hip_runtime.h>

// Contracter: out[z,u,k] = sum_{i,j} x1[z,u,i] * x2[z,u,j] * ww3j[u,k,i,j]
// where ww3j[u,k,i,j] = sum_p weights[u,p] * w3j[p,k,i,j].
// Z=50000, MUL=64 channels, BASE=9 (irreps 0e+1o+2e), 11 paths. All fp32.
//
// v6 = v5 with the band-mapping bug fixed.
// v4/v5 bug: wwr registers hold the CG row for channel u == lane, but the
// band loop assigned lane to channel (lane&31)+32q -> half the lanes used
// the wrong channel's weights (identical absmax in v4 and v5 proved the
// failure was structural, not the support table). Fix: lane processes its
// OWN channel u = lane, for both rows r=0,1 of the chunk.
//   band read addr = r*584 + lane*9 + i : lane*9 mod 32 (9 coprime 32)
//   -> lanes 0..31 cover all 32 banks, lanes 32..63 alias exactly 2-way
//   = conflict-free (2-way is free on CDNA4).
//
// Support table (re-verified constructively this round):
//  - delta blocks for every coupling involving l=0 (P0..P4,P7,P9).
//  - 1x1->2 / 1x2->1 / 2x1->1: 11 entries each, the components of the
//    traceless-symmetric vector product in basis (y,z,x)/(xy,yz,z2,zx,x2y2),
//    related by permutation symmetry of the 3j tensor.
//  - 2x2->2: 25 entries from {Ma,Mb}/2 over the 5 basis matrices
//    (all 15 products multiplied out explicitly; {xy, x2-y2} = 0).
//  Union = 83 nonzeros; pack_kernel reads actual w3j values so superset
//  entries are harmless.
//
// Kernel structure (unchanged from v4/v5):
//  - pack_kernel folds weights into wws[n][u] (83 x 64, coalesced in u).
//  - tp_kernel: lane = u. 83 ww values in REGISTERS, loaded once per wave,
//    amortized over ~6 chunks by a persistent grid. Per chunk (2 z-rows):
//    coalesced float4 loads -> wave-private LDS strips (stride 584 floats:
//    16B-aligned b128 writes); per-lane band reads (conflict-free, above);
//    sparse contraction (~83 FMA + ~60 mul); write o over the consumed x1
//    band; coalesced float4 store. NO __syncthreads (strips wave-private,
//    same-wave DS ops in-order).

#define MUL    64
#define BASE   9
#define NPATH  11
#define NNZ    83
#define RPC    2              // z-rows per chunk per wave
#define STRIDE 584            // padded row stride in floats (576+8)
#define SFL    (RPC * STRIDE) // floats per strip (1168)
#define F4T    (RPC * 576 / 4)// float4 slots per chunk per array (288)

// (k,i,j) support, grouped by path:
// P0(0,0,0) P1(0,1,1) P2(0,2,2) P3(1,0,1) P4(1,1,0) P5(1,1,2) P6(1,2,1)
// P7(2,0,2) P8(2,1,1) P9(2,2,0) P10(2,2,2)
constexpr unsigned char cK[NNZ] = {
    0,                                  // P0
    1,2,3,                              // P1
    4,5,6,7,8,                          // P2
    1,2,3,                              // P3
    0,0,0,                              // P4
    4,4,5,5,6,6,6,7,7,8,8,              // P5
    3,1,2,1,1,2,3,3,2,1,3,              // P6
    4,5,6,7,8,                          // P7
    3,1,2,1,1,2,3,3,2,1,3,              // P8
    0,0,0,0,0,                          // P9
    6,6,8,6,6,8,6, 7,7, 4,4, 5,5, 5,5, 4,4, 5,5, 7,7, 8,8, 7,7}; // P10
constexpr unsigned char cI[NNZ] = {
    0,
    0,0,0,
    0,0,0,0,0,
    1,2,3,
    1,2,3,
    1,3,1,2,1,2,3,2,3,1,3,
    1,3,1,2,1,2,3,2,3,1,3,
    4,5,6,7,8,
    4,4,5,5,6,6,6,7,7,8,8,
    4,5,6,7,8,
    4,5,5,6,7,7,8, 4,5, 4,6, 4,7, 5,6, 5,7, 5,8, 6,7, 6,8, 7,8};
constexpr unsigned char cJ[NNZ] = {
    0,
    1,2,3,
    4,5,6,7,8,
    0,0,0,
    1,2,3,
    3,1,2,1,1,2,3,3,2,1,3,
    4,4,5,5,6,6,6,7,7,8,8,
    0,0,0,0,0,
    1,3,1,2,1,2,3,2,3,1,3,
    4,5,6,7,8,
    4,5,5,6,7,7,8, 5,4, 6,4, 7,4, 6,5, 7,5, 8,5, 7,6, 8,6, 8,7};

// Fold weights into the packed sparse CG table: wws[n*64+u] =
// sum_p weights[u,p] * w3j[p, K[n], I[n], J[n]].
__global__ __launch_bounds__(256) void pack_kernel(
    const float* __restrict__ weights,   // (64, 11)
    const float* __restrict__ w3j,       // (11, 9, 9, 9)
    float*       __restrict__ wws)       // (83, 64) out
{
    int t = blockIdx.x * 256 + threadIdx.x;
    if (t >= NNZ * MUL) return;
    int n = t >> 6;
    int u = t & 63;
    int idx = cK[n] * 81 + cI[n] * 9 + cJ[n];
    float acc = 0.f;
#pragma unroll
    for (int p = 0; p < NPATH; ++p)
        acc = fmaf(weights[u * NPATH + p], w3j[p * 729 + idx], acc);
    wws[t] = acc;
}

__global__ __launch_bounds__(256) void tp_kernel(
    const float* __restrict__ x1,
    const float* __restrict__ x2,
    const float* __restrict__ wws,       // (83, 64)
    float*       __restrict__ out,
    int Z, int nchunks)
{
    __shared__ float lds[4 * 2 * SFL];   // 4 waves x (s1,s2) = 37376 B

    int wave = threadIdx.x >> 6;
    int lane = threadIdx.x & 63;
    float* s1 = lds + wave * (2 * SFL);
    float* s2 = s1 + SFL;

    // Per-lane sparse CG row for channel u == lane: 83 VGPRs, loaded once,
    // statically indexed below (fully unrolled) -> stays in registers.
    float wwr[NNZ];
#pragma unroll
    for (int n = 0; n < NNZ; ++n) wwr[n] = wws[n * MUL + lane];

    int stride = gridDim.x * 4;

    for (int c = blockIdx.x * 4 + wave; c < nchunks; c += stride) {
        size_t base = (size_t)c * (RPC * 576);

        // ---- stage: coalesced float4 loads -> private strips ----
#pragma unroll
        for (int t = 0; t < 5; ++t) {
            int f = t * 64 + lane;                 // float4 slot in [0,288)
            if (f < F4T) {
                int rr = f / 144;                  // z-row within chunk
                int z  = c * RPC + rr;
                float4 v1 = make_float4(0.f, 0.f, 0.f, 0.f);
                float4 v2 = make_float4(0.f, 0.f, 0.f, 0.f);
                if (z < Z) {
                    v1 = *(const float4*)(x1 + base + f * 4);
                    v2 = *(const float4*)(x2 + base + f * 4);
                }
                int off = f * 4 + 8 * rr;          // rr*STRIDE + (4f-576rr)
                *(float4*)(s1 + off) = v1;
                *(float4*)(s2 + off) = v2;
            }
        }

        // ---- bands: lane handles channel u = lane, rows r = 0..1 ----
#pragma unroll
        for (int r = 0; r < RPC; ++r) {
            int bo = r * STRIDE + lane * 9;        // (lane*9)%32: 2-way, free
            float X1v[BASE], X2v[BASE];
#pragma unroll
            for (int i = 0; i < BASE; ++i) {
                X1v[i] = s1[bo + i];
                X2v[i] = s2[bo + i];
            }
            float o[BASE];
#pragma unroll
            for (int k = 0; k < BASE; ++k) o[k] = 0.f;
#pragma unroll
            for (int n = 0; n < NNZ; ++n)
                o[cK[n]] = fmaf(wwr[n], X1v[cI[n]] * X2v[cJ[n]], o[cK[n]]);
            // Write o over this lane's own x1-strip band (just consumed;
            // per-lane slices disjoint; same-wave DS ops in-order).
#pragma unroll
            for (int k = 0; k < BASE; ++k) s1[bo + k] = o[k];
        }

        // ---- store: coalesced float4 stores from the (now out-) strip ----
#pragma unroll
        for (int t = 0; t < 5; ++t) {
            int f = t * 64 + lane;
            if (f < F4T) {
                int rr = f / 144;
                int z  = c * RPC + rr;
                if (z < Z) {
                    int off = f * 4 + 8 * rr;
                    *(float4*)(out + base + f * 4) = *(const float4*)(s1 + off);
                }
            }
        }
    }
}

extern "C" void kernel_launch(void* const* d_in, const int* in_sizes, int n_in,
                              void* d_out, int out_size, void* d_ws, size_t ws_size,
                              hipStream_t stream) {
    const float* x1  = (const float*)d_in[0];
    const float* x2  = (const float*)d_in[1];
    const float* w   = (const float*)d_in[2];   // (64, 11)
    const float* w3j = (const float*)d_in[3];   // (11, 9, 9, 9)
    float* out = (float*)d_out;
    float* wws = (float*)d_ws;                  // (83, 64) packed sparse CG

    int Z = in_sizes[0] / (MUL * BASE);

    pack_kernel<<<(NNZ * MUL + 255) / 256, 256, 0, stream>>>(w, w3j, wws);

    int nchunks = (Z + RPC - 1) / RPC;
    // Persistent grid: 1024 blocks x 4 waves; each wave loops ~6 chunks,
    // amortizing its one-time 83-load ww fill.
    tp_kernel<<<1024, 256, 0, stream>>>(x1, x2, wws, out, Z, nchunks);
}